// Round 1
// baseline (340.630 us; speedup 1.0000x reference)
//
#include <hip/hip_runtime.h>

#define DIMG 160

// ---------- Pass Z: raw input -> 5 channels, z-axis dilated strided box sum ----------
// out layout: 5 channels, each [B][160][160][n], z' contiguous.
__global__ void pass_z_kernel(const float* __restrict__ in, const float* __restrict__ tg,
                              float* __restrict__ out, int B, int n, int k, int d, int s) {
    const int D = DIMG;
    const long total = (long)B * D * D * n;   // == per-channel stride
    long idx = (long)blockIdx.x * blockDim.x + threadIdx.x;
    if (idx >= total) return;
    int z = (int)(idx % n);
    long t = idx / n;
    int y = (int)(t % D); t /= D;
    int x = (int)(t % D);
    int b = (int)(t / D);
    const long base = (((long)b * D + x) * D + y) * D + (long)z * s;
    const float* ip = in + base;
    const float* tp = tg + base;
    float sx = 0.f, sy = 0.f, sxx = 0.f, syy = 0.f, sxy = 0.f;
#pragma unroll 4
    for (int i = 0; i < k; ++i) {
        float a = ip[(long)i * d];
        float c = tp[(long)i * d];
        sx += a; sy += c; sxx += a * a; syy += c * c; sxy += a * c;
    }
    out[idx]             = sx;
    out[idx + total]     = sy;
    out[idx + 2 * total] = sxx;
    out[idx + 3 * total] = syy;
    out[idx + 4 * total] = sxy;
}

// ---------- Pass Y: [B][160][160][n] -> [B][160][n][n] ----------
__global__ void pass_y_kernel(const float* __restrict__ in, float* __restrict__ out,
                              int B, int n, int k, int d, int s) {
    const int D = DIMG;
    const long chanIn = (long)B * D * D * n;
    const long total  = (long)B * D * n * n;  // per-channel out stride
    long idx = (long)blockIdx.x * blockDim.x + threadIdx.x;
    if (idx >= total) return;
    int z = (int)(idx % n);
    long t = idx / n;
    int yp = (int)(t % n); t /= n;
    int x  = (int)(t % D);
    int b  = (int)(t / D);
    const float* base = in + ((long)b * D + x) * D * n + (long)(yp * s) * n + z;
    float s0 = 0.f, s1 = 0.f, s2 = 0.f, s3 = 0.f, s4 = 0.f;
    for (int i = 0; i < k; ++i) {
        long off = (long)i * d * n;
        s0 += base[off];
        s1 += base[off + chanIn];
        s2 += base[off + 2 * chanIn];
        s3 += base[off + 3 * chanIn];
        s4 += base[off + 4 * chanIn];
    }
    out[idx]             = s0;
    out[idx + total]     = s1;
    out[idx + 2 * total] = s2;
    out[idx + 3 * total] = s3;
    out[idx + 4 * total] = s4;
}

// ---------- Pass X + LNCC + reduction ----------
// in: 5 channels of [B][160][n][n]; accumulate sum of lncc into *acc.
__global__ void pass_x_lncc_kernel(const float* __restrict__ in, float* __restrict__ acc,
                                   int B, int n, int k, int d, int s, float numel) {
    const int D = DIMG;
    const long chanIn = (long)B * D * n * n;
    const long total  = (long)B * n * (long)n * n;
    long idx = (long)blockIdx.x * blockDim.x + threadIdx.x;
    float v = 0.f;
    if (idx < total) {
        int z = (int)(idx % n);
        long t = idx / n;
        int y  = (int)(t % n); t /= n;
        int xp = (int)(t % n);
        int b  = (int)(t / n);
        const float* base = in + (long)b * D * n * n + (long)(xp * s) * n * n + (long)y * n + z;
        float s0 = 0.f, s1 = 0.f, s2 = 0.f, s3 = 0.f, s4 = 0.f;
        for (int i = 0; i < k; ++i) {
            long off = (long)i * d * n * n;
            s0 += base[off];
            s1 += base[off + chanIn];
            s2 += base[off + 2 * chanIn];
            s3 += base[off + 3 * chanIn];
            s4 += base[off + 4 * chanIn];
        }
        float xm = s0 / numel, ym = s1 / numel;
        float cross = s4 - ym * s0 - xm * s1 + ym * xm * numel;
        float xvar  = s2 - 2.f * xm * s0 + xm * xm * numel;
        float yvar  = s3 - 2.f * ym * s1 + ym * ym * numel;
        v = cross * cross / (xvar * yvar + 1e-5f);
    }
    // block (256-thread) reduction: 64-lane shuffle then LDS across 4 waves
    __shared__ float wsum[4];
    for (int o = 32; o > 0; o >>= 1) v += __shfl_down(v, o, 64);
    int lane = threadIdx.x & 63, wid = threadIdx.x >> 6;
    if (lane == 0) wsum[wid] = v;
    __syncthreads();
    if (threadIdx.x == 0) {
        atomicAdd(acc, wsum[0] + wsum[1] + wsum[2] + wsum[3]);
    }
}

__global__ void finalize_kernel(const float* __restrict__ acc, float* __restrict__ out,
                                float c0, float c1, float c2,
                                float w0, float w1, float w2) {
    if (threadIdx.x == 0 && blockIdx.x == 0) {
        out[0] = w0 * (1.f - acc[0] / c0) +
                 w1 * (1.f - acc[1] / c1) +
                 w2 * (1.f - acc[2] / c2);
    }
}

extern "C" void kernel_launch(void* const* d_in, const int* in_sizes, int n_in,
                              void* d_out, int out_size, void* d_ws, size_t ws_size,
                              hipStream_t stream) {
    const float* input  = (const float*)d_in[0];
    const float* target = (const float*)d_in[1];
    float* out = (float*)d_out;
    const int D = DIMG;
    // img 160 -> max_scale 160 > 128 branch of _scale_config
    const int   KS[3] = {10, 20, 40};
    const int   DS[3] = {2, 2, 2};
    const int   SS[3] = {2, 5, 10};
    const int   NS[3] = {71, 25, 9};   // (160 - ((k-1)*d+1))/s + 1
    const float WTS[3] = {0.1f, 0.3f, 0.6f};

    char* ws = (char*)d_ws;
    float* acc = (float*)ws;              // 3 floats, padded to 256B
    const size_t accPad = 256;
    const int nmax = 71;
    const size_t buf1PerB = 5ull * D * D * nmax;       // 9,088,000 floats
    const size_t buf2PerB = 5ull * D * nmax * nmax;    // 4,032,800 floats
    const size_t need2 = accPad + (buf1PerB + buf2PerB) * 2 * sizeof(float);
    const int Bstep = (ws_size >= need2) ? 2 : 1;      // batched if scratch allows
    float* buf1 = (float*)(ws + accPad);
    float* buf2 = buf1 + buf1PerB * Bstep;

    hipMemsetAsync(acc, 0, 3 * sizeof(float), stream);

    for (int sc = 0; sc < 3; ++sc) {
        const int k = KS[sc], d = DS[sc], s = SS[sc], n = NS[sc];
        const float numel = (float)k * (float)k * (float)k;
        for (int b0 = 0; b0 < 2; b0 += Bstep) {
            const int B = Bstep;
            const float* ip = input  + (size_t)b0 * D * D * D;
            const float* tp = target + (size_t)b0 * D * D * D;
            long t1 = (long)B * D * D * n;
            pass_z_kernel<<<dim3((unsigned)((t1 + 255) / 256)), dim3(256), 0, stream>>>(
                ip, tp, buf1, B, n, k, d, s);
            long t2 = (long)B * D * n * n;
            pass_y_kernel<<<dim3((unsigned)((t2 + 255) / 256)), dim3(256), 0, stream>>>(
                buf1, buf2, B, n, k, d, s);
            long t3 = (long)B * n * (long)n * n;
            pass_x_lncc_kernel<<<dim3((unsigned)((t3 + 255) / 256)), dim3(256), 0, stream>>>(
                buf2, acc + sc, B, n, k, d, s, numel);
        }
    }
    finalize_kernel<<<dim3(1), dim3(64), 0, stream>>>(
        acc, out,
        2.f * NS[0] * NS[0] * NS[0],
        2.f * NS[1] * NS[1] * NS[1],
        2.f * NS[2] * NS[2] * NS[2],
        WTS[0], WTS[1], WTS[2]);
}

// Round 2
// 283.793 us; speedup vs baseline: 1.2003x; 1.2003x over previous
//
#include <hip/hip_runtime.h>

#define DD 160

// ================= Fused Z pass =================
// One wave per (b,x,y) row. Builds stride-2 prefix sums of the 5 channels
// (x, y, x^2, y^2, x*y) in registers via shuffles, stores S[-2..159] (+2 shift)
// to LDS, then every scale's dilated window sum = S[b+2k] - S[b] (2 reads).
// Output layout per scale: [ch][b][x][y][z'], chan stride = B*DD*DD*n.
__global__ __launch_bounds__(256) void fz_kernel(
    const float* __restrict__ in, const float* __restrict__ tg,
    float* __restrict__ z0, float* __restrict__ z1, float* __restrict__ z2,
    int B) {
    __shared__ float S[4][5][162];
    const int wid  = threadIdx.x >> 6;
    const int lane = threadIdx.x & 63;
    const long R   = (long)B * DD * DD;
    const long row = (long)blockIdx.x * 4 + wid;   // grid is exactly R/4 blocks
    const float* ip = in + row * DD;
    const float* tp = tg + row * DD;

    float a0 = ip[lane], a1 = ip[lane + 64];
    float b0 = tp[lane], b1 = tp[lane + 64];
    float a2 = 0.f, b2 = 0.f;
    if (lane < 32) { a2 = ip[lane + 128]; b2 = tp[lane + 128]; }

    float* Sw = &S[wid][0][0];

    auto scan3 = [&](float v0, float v1, float v2, float* outp) {
        // stride-2 (same-parity) inclusive scan over z = word*64 + lane
#pragma unroll
        for (int o = 2; o <= 32; o <<= 1) {
            float t0 = __shfl_up(v0, o);
            float t1 = __shfl_up(v1, o);
            float t2 = __shfl_up(v2, o);
            if (lane >= o) { v0 += t0; v1 += t1; v2 += t2; }
        }
        // carry word0 -> word1 -> word2 (parity-matched: lane 62 even, 63 odd)
        float c1 = __shfl(v0, 62 + (lane & 1));
        v1 += c1;
        float c2 = __shfl(v1, 62 + (lane & 1));
        v2 += c2;
        if (lane < 2) outp[lane] = 0.f;      // S[-2], S[-1]
        outp[lane + 2]  = v0;                // z = lane
        outp[lane + 66] = v1;                // z = 64 + lane
        if (lane < 32) outp[lane + 130] = v2; // z = 128 + lane
    };

    scan3(a0,       a1,       a2,       Sw + 0 * 162);   // x
    scan3(b0,       b1,       b2,       Sw + 1 * 162);   // y
    scan3(a0 * a0,  a1 * a1,  a2 * a2,  Sw + 2 * 162);   // x^2
    scan3(b0 * b0,  b1 * b1,  b2 * b2,  Sw + 3 * 162);   // y^2
    scan3(a0 * b0,  a1 * b1,  a2 * b2,  Sw + 4 * 162);   // x*y
    __syncthreads();

    const long C0 = R * 71, C1 = R * 25, C2 = R * 9;
    // 105 window tasks: 71 (k=10,s=2) + 25 (k=20,s=5) + 9 (k=40,s=10)
    for (int t = lane; t < 105; t += 64) {
        float* buf; long C; int n, zp, lo, hi;
        if (t < 71)      { buf = z0; C = C0; n = 71; zp = t;      lo = zp * 2;  hi = lo + 20; }
        else if (t < 96) { buf = z1; C = C1; n = 25; zp = t - 71; lo = zp * 5;  hi = lo + 40; }
        else             { buf = z2; C = C2; n = 9;  zp = t - 96; lo = zp * 10; hi = lo + 80; }
        long o = row * n + zp;
#pragma unroll
        for (int ch = 0; ch < 5; ++ch)
            buf[o + (long)ch * C] = Sw[ch * 162 + hi] - Sw[ch * 162 + lo];
    }
}

// ================= Y pass (per scale) =================
// One block per (ch,b,x) plane: LDS-stage the contiguous [160][n] plane,
// per-thread sliding-window recurrence along y' (parity chains, step 2,
// remove/add s taps). Output plane: contiguous [n][n] at planeIdx*n*n.
__global__ __launch_bounds__(256) void yk_kernel(
    const float* __restrict__ src, float* __restrict__ dst,
    int n, int k, int s, int CL) {
    extern __shared__ float pl[];            // [160][n]
    const long pid = blockIdx.x;             // ch*(B*DD) + b*DD + x
    const float* sp = src + pid * DD * n;
    float* dp = dst + (long)pid * n * n;
    const int len = DD * n;
    for (int i = threadIdx.x; i < len; i += blockDim.x) pl[i] = sp[i];
    __syncthreads();

    const int npE = (n + 1) >> 1;            // even-parity output count
    const int CC  = (npE + CL - 1) / CL;     // chunks per parity
    const int T   = n * 2 * CC;
    for (int t = threadIdx.x; t < T; t += blockDim.x) {
        int zp = t % n;
        int rr = t / n;
        int p  = rr & 1;
        int c  = rr >> 1;
        int y0 = p + 2 * c * CL;
        if (y0 >= n) continue;
        int cnt = min(CL, ((n - y0) + 1) >> 1);   // outputs y0, y0+2, ...
        float w = 0.f;
        int base = y0 * s;
        for (int i = 0; i < k; ++i) w += pl[(base + 2 * i) * n + zp];
        dp[y0 * n + zp] = w;
        int yp = y0;
        for (int q = 1; q < cnt; ++q) {
            int ob = yp * s;
            for (int j = 0; j < s; ++j) {
                w -= pl[(ob + 2 * j) * n + zp];
                w += pl[(ob + 2 * k + 2 * j) * n + zp];
            }
            yp += 2;
            dp[yp * n + zp] = w;
        }
    }
}

// ================= X pass + LNCC + reduction (unchanged, known-correct) ====
__global__ __launch_bounds__(256) void px_kernel(
    const float* __restrict__ in, float* __restrict__ acc,
    int B, int n, int k, int d, int s, float numel) {
    const int D = DD;
    const long chanIn = (long)B * D * n * n;
    const long total  = (long)B * n * (long)n * n;
    long idx = (long)blockIdx.x * blockDim.x + threadIdx.x;
    float v = 0.f;
    if (idx < total) {
        int z = (int)(idx % n);
        long t = idx / n;
        int y  = (int)(t % n); t /= n;
        int xp = (int)(t % n);
        int b  = (int)(t / n);
        const float* base = in + (long)b * D * n * n + (long)(xp * s) * n * n + (long)y * n + z;
        float s0 = 0.f, s1 = 0.f, s2 = 0.f, s3 = 0.f, s4 = 0.f;
        for (int i = 0; i < k; ++i) {
            long off = (long)i * d * n * n;
            s0 += base[off];
            s1 += base[off + chanIn];
            s2 += base[off + 2 * chanIn];
            s3 += base[off + 3 * chanIn];
            s4 += base[off + 4 * chanIn];
        }
        float xm = s0 / numel, ym = s1 / numel;
        float cross = s4 - ym * s0 - xm * s1 + ym * xm * numel;
        float xvar  = s2 - 2.f * xm * s0 + xm * xm * numel;
        float yvar  = s3 - 2.f * ym * s1 + ym * ym * numel;
        v = cross * cross / (xvar * yvar + 1e-5f);
    }
    __shared__ float wsum[4];
    for (int o = 32; o > 0; o >>= 1) v += __shfl_down(v, o, 64);
    int lane = threadIdx.x & 63, wid = threadIdx.x >> 6;
    if (lane == 0) wsum[wid] = v;
    __syncthreads();
    if (threadIdx.x == 0) atomicAdd(acc, wsum[0] + wsum[1] + wsum[2] + wsum[3]);
}

__global__ void finalize_kernel(const float* __restrict__ acc, float* __restrict__ out,
                                float c0, float c1, float c2,
                                float w0, float w1, float w2) {
    if (threadIdx.x == 0 && blockIdx.x == 0) {
        out[0] = w0 * (1.f - acc[0] / c0) +
                 w1 * (1.f - acc[1] / c1) +
                 w2 * (1.f - acc[2] / c2);
    }
}

extern "C" void kernel_launch(void* const* d_in, const int* in_sizes, int n_in,
                              void* d_out, int out_size, void* d_ws, size_t ws_size,
                              hipStream_t stream) {
    const float* input  = (const float*)d_in[0];
    const float* target = (const float*)d_in[1];
    float* out = (float*)d_out;

    const int   NS[3]  = {71, 25, 9};
    const int   KS[3]  = {10, 20, 40};
    const int   SS[3]  = {2, 5, 10};
    const int   CLs[3] = {9, 7, 5};     // y'-outputs per recurrence chunk

    char* ws = (char*)d_ws;
    float* acc = (float*)ws;
    const size_t accPad = 256;

    // full-batch need: z-bufs 5*R*(71+25+9) + y-buf 5*R/160*71^2 floats, R=2*160*160
    const size_t zF  = 5ull * 2 * DD * DD * (71 + 25 + 9);      // 26,880,000 floats
    const size_t yF  = 5ull * 2 * DD * 71 * 71;                 //  8,065,600 floats
    const size_t fullNeed = accPad + (zF + yF) * sizeof(float); // ~139.8 MB
    const int NB = (ws_size >= fullNeed) ? 2 : 1;

    const long R = (long)NB * DD * DD;
    float* z0 = (float*)(ws + accPad);
    float* z1 = z0 + 5ull * R * 71;
    float* z2 = z1 + 5ull * R * 25;
    float* yb = z2 + 5ull * R * 9;     // reused across scales (max size = scale 0)

    hipMemsetAsync(acc, 0, 3 * sizeof(float), stream);

    for (int b0 = 0; b0 < 2; b0 += NB) {
        const float* ip = input  + (size_t)b0 * DD * DD * DD;
        const float* tp = target + (size_t)b0 * DD * DD * DD;
        fz_kernel<<<dim3((unsigned)(R / 4)), dim3(256), 0, stream>>>(ip, tp, z0, z1, z2, NB);
        for (int sc = 0; sc < 3; ++sc) {
            const int n = NS[sc], k = KS[sc], s = SS[sc];
            float* zb = (sc == 0) ? z0 : (sc == 1) ? z1 : z2;
            const int planes = 5 * NB * DD;
            const size_t lds = (size_t)DD * n * sizeof(float);
            yk_kernel<<<dim3(planes), dim3(256), lds, stream>>>(zb, yb, n, k, s, CLs[sc]);
            const long t3 = (long)NB * n * (long)n * n;
            px_kernel<<<dim3((unsigned)((t3 + 255) / 256)), dim3(256), 0, stream>>>(
                yb, acc + sc, NB, n, k, 2, s, (float)k * (float)k * (float)k);
        }
    }
    finalize_kernel<<<dim3(1), dim3(64), 0, stream>>>(
        acc, out,
        2.f * NS[0] * NS[0] * NS[0],
        2.f * NS[1] * NS[1] * NS[1],
        2.f * NS[2] * NS[2] * NS[2],
        0.1f, 0.3f, 0.6f);
}